// Round 1
// baseline (544.280 us; speedup 1.0000x reference)
//
#include <hip/hip_runtime.h>

#define N_NODES 50000
#define N_EDGES 800000
#define F_IN 64
#define F_HID 64
#define F_OUT 32

// One wave (64 lanes) per edge: lane i handles feature i.
// agg[dst][i] += x[src][i]; lane 0 optionally counts in-degree.
__global__ __launch_bounds__(256)
void scatter_edges(const float* __restrict__ x,
                   const int* __restrict__ src,
                   const int* __restrict__ dst,
                   float* __restrict__ agg,
                   float* __restrict__ deg) {
    int gid  = blockIdx.x * blockDim.x + threadIdx.x;
    int edge = gid >> 6;
    int lane = threadIdx.x & 63;
    if (edge >= N_EDGES) return;
    int s = src[edge];
    int d = dst[edge];
    float v = x[s * 64 + lane];
    atomicAdd(&agg[d * 64 + lane], v);
    if (deg != nullptr && lane == 0) {
        atomicAdd(&deg[d], 1.0f);
    }
}

// Fused SAGE layer: out[v] = act( x[v] @ Wself + (agg[v]/max(deg,1)) @ Wneigh + b )
// FOUT threads per node ("slot"); weights + per-node rows staged in LDS.
template <int FOUT, bool RELU>
__global__ __launch_bounds__(256)
void sage_layer(const float* __restrict__ x,
                const float* __restrict__ agg,
                const float* __restrict__ deg,
                const float* __restrict__ Wself,
                const float* __restrict__ Wneigh,
                const float* __restrict__ bias,
                float* __restrict__ out) {
    constexpr int SLOTS = 256 / FOUT;
    __shared__ float Ws[64 * FOUT];
    __shared__ float Wn[64 * FOUT];
    __shared__ float xs[SLOTS][64];
    __shared__ float ns[SLOTS][64];

    for (int i = threadIdx.x; i < 64 * FOUT; i += 256) {
        Ws[i] = Wself[i];
        Wn[i] = Wneigh[i];
    }
    const int j    = threadIdx.x % FOUT;
    const int slot = threadIdx.x / FOUT;
    const float bj = bias[j];
    __syncthreads();

    // Uniform trip count across the block so __syncthreads is safe.
    for (int vbase = blockIdx.x * SLOTS; vbase < N_NODES; vbase += gridDim.x * SLOTS) {
        const int v = vbase + slot;
        const bool valid = (v < N_NODES);
        if (valid) {
            const float inv = 1.0f / fmaxf(deg[v], 1.0f);
            for (int k = j; k < 64; k += FOUT) {
                xs[slot][k] = x[v * 64 + k];
                ns[slot][k] = agg[v * 64 + k] * inv;
            }
        }
        __syncthreads();
        if (valid) {
            float acc = bj;
#pragma unroll
            for (int k = 0; k < 64; ++k) {
                acc += xs[slot][k] * Ws[k * FOUT + j];
                acc += ns[slot][k] * Wn[k * FOUT + j];
            }
            if (RELU) acc = fmaxf(acc, 0.0f);
            out[v * FOUT + j] = acc;
        }
        __syncthreads();
    }
}

extern "C" void kernel_launch(void* const* d_in, const int* in_sizes, int n_in,
                              void* d_out, int out_size, void* d_ws, size_t ws_size,
                              hipStream_t stream) {
    const float* features = (const float*)d_in[0];   // [N, 64]
    const float* W_self1  = (const float*)d_in[1];   // [64, 64]
    const float* W_neigh1 = (const float*)d_in[2];   // [64, 64]
    const float* b1       = (const float*)d_in[3];   // [64]
    const float* W_self2  = (const float*)d_in[4];   // [64, 32]
    const float* W_neigh2 = (const float*)d_in[5];   // [64, 32]
    const float* b2       = (const float*)d_in[6];   // [32]
    const int*   src      = (const int*)d_in[7];     // [E]
    const int*   dst      = (const int*)d_in[8];     // [E]
    float*       out      = (float*)d_out;           // [N, 32]

    // Workspace layout (fp32):
    //   agg : N*64 floats (12.8 MB)  -- reused for both layers
    //   h   : N*64 floats (12.8 MB)
    //   deg : N    floats (0.2 MB)
    float* agg = (float*)d_ws;
    float* h   = agg + (size_t)N_NODES * 64;
    float* deg = h   + (size_t)N_NODES * 64;

    const size_t agg_bytes = (size_t)N_NODES * 64 * sizeof(float);
    const size_t deg_bytes = (size_t)N_NODES * sizeof(float);

    const int scatter_blocks = (N_EDGES * 64) / 256;   // one wave per edge
    const int layer_blocks   = 1024;

    // ---- Layer 1 ----
    hipMemsetAsync(agg, 0, agg_bytes, stream);
    hipMemsetAsync(deg, 0, deg_bytes, stream);
    scatter_edges<<<scatter_blocks, 256, 0, stream>>>(features, src, dst, agg, deg);
    sage_layer<64, true><<<layer_blocks, 256, 0, stream>>>(
        features, agg, deg, W_self1, W_neigh1, b1, h);

    // ---- Layer 2 ----
    hipMemsetAsync(agg, 0, agg_bytes, stream);
    scatter_edges<<<scatter_blocks, 256, 0, stream>>>(h, src, dst, agg, nullptr);
    sage_layer<32, false><<<layer_blocks, 256, 0, stream>>>(
        h, agg, deg, W_self2, W_neigh2, b2, out);
}

// Round 2
// 318.571 us; speedup vs baseline: 1.7085x; 1.7085x over previous
//
#include <hip/hip_runtime.h>

#define N_NODES 50000
#define N_EDGES 800000
#define SCAN_BLOCKS 196   // ceil(50000/256)

// ---------------- CSR build ----------------

__global__ __launch_bounds__(256)
void hist_kernel(const int* __restrict__ dst, int* __restrict__ counts) {
    int e = blockIdx.x * blockDim.x + threadIdx.x;
    if (e < N_EDGES) atomicAdd(&counts[dst[e]], 1);
}

__global__ __launch_bounds__(256)
void scan_blocks_kernel(const int* __restrict__ counts, int* __restrict__ partials) {
    __shared__ int buf[256];
    int i = blockIdx.x * 256 + threadIdx.x;
    buf[threadIdx.x] = (i < N_NODES) ? counts[i] : 0;
    __syncthreads();
    for (int off = 128; off > 0; off >>= 1) {
        if (threadIdx.x < off) buf[threadIdx.x] += buf[threadIdx.x + off];
        __syncthreads();
    }
    if (threadIdx.x == 0) partials[blockIdx.x] = buf[0];
}

__global__ void scan_top_kernel(int* __restrict__ partials) {
    if (threadIdx.x == 0 && blockIdx.x == 0) {
        int acc = 0;
        for (int b = 0; b < SCAN_BLOCKS; ++b) {
            int v = partials[b];
            partials[b] = acc;   // exclusive
            acc += v;
        }
    }
}

__global__ __launch_bounds__(256)
void scan_apply_kernel(const int* __restrict__ counts, const int* __restrict__ offsets,
                       int* __restrict__ row_ptr, int* __restrict__ cursor) {
    __shared__ int buf[256];
    int t = threadIdx.x;
    int i = blockIdx.x * 256 + t;
    int v = (i < N_NODES) ? counts[i] : 0;
    buf[t] = v;
    __syncthreads();
    for (int off = 1; off < 256; off <<= 1) {
        int add = (t >= off) ? buf[t - off] : 0;
        __syncthreads();
        buf[t] += add;
        __syncthreads();
    }
    if (i < N_NODES) {
        int rp = offsets[blockIdx.x] + buf[t] - v;   // exclusive scan
        row_ptr[i] = rp;
        cursor[i]  = rp;
    }
}

__global__ __launch_bounds__(256)
void fill_kernel(const int* __restrict__ src, const int* __restrict__ dst,
                 int* __restrict__ cursor, int* __restrict__ csr_src) {
    int e = blockIdx.x * blockDim.x + threadIdx.x;
    if (e < N_EDGES) {
        int d = dst[e];
        int pos = atomicAdd(&cursor[d], 1);
        csr_src[pos] = src[e];
    }
}

// ---------------- Gather-based mean aggregation ----------------
// FW threads per node; lane j = feature j. Output already divided by max(deg,1).
template <int FW>
__global__ __launch_bounds__(256)
void gather_mean(const float* __restrict__ x,
                 const int* __restrict__ row_ptr, const int* __restrict__ counts,
                 const int* __restrict__ csr_src, float* __restrict__ out) {
    constexpr int SLOTS = 256 / FW;
    int j = threadIdx.x % FW;
    int slot = threadIdx.x / FW;
    int v = blockIdx.x * SLOTS + slot;
    if (v >= N_NODES) return;
    int start = row_ptr[v];
    int cnt = counts[v];
    float acc = 0.0f;
    int t = 0;
    for (; t + 4 <= cnt; t += 4) {
        int s0 = csr_src[start + t + 0];
        int s1 = csr_src[start + t + 1];
        int s2 = csr_src[start + t + 2];
        int s3 = csr_src[start + t + 3];
        float v0 = x[(size_t)s0 * FW + j];
        float v1 = x[(size_t)s1 * FW + j];
        float v2 = x[(size_t)s2 * FW + j];
        float v3 = x[(size_t)s3 * FW + j];
        acc += v0 + v1 + v2 + v3;
    }
    for (; t < cnt; ++t) {
        int s = csr_src[start + t];
        acc += x[(size_t)s * FW + j];
    }
    out[(size_t)v * FW + j] = acc / (float)max(cnt, 1);
}

// ---------------- Layer 1 fused: h = relu(x@Ws1 + nmean@Wn1 + b1); g = h@Wn2 ----------------
__global__ __launch_bounds__(256)
void sage_layer1_fused(const float* __restrict__ x, const float* __restrict__ nmean,
                       const float* __restrict__ Ws1, const float* __restrict__ Wn1,
                       const float* __restrict__ b1, const float* __restrict__ Wn2,
                       float* __restrict__ h, float* __restrict__ g) {
    __shared__ float Ws[64 * 64];
    __shared__ float Wn[64 * 64];
    __shared__ float W2[64 * 32];
    __shared__ float xs[4][64];
    __shared__ float ns[4][64];
    __shared__ float hs[4][64];

    for (int i = threadIdx.x; i < 64 * 64; i += 256) { Ws[i] = Ws1[i]; Wn[i] = Wn1[i]; }
    for (int i = threadIdx.x; i < 64 * 32; i += 256) { W2[i] = Wn2[i]; }
    const int j = threadIdx.x & 63;
    const int slot = threadIdx.x >> 6;
    const float bj = b1[j];
    __syncthreads();

    const int v = blockIdx.x * 4 + slot;
    const bool valid = (v < N_NODES);
    if (valid) {
        xs[slot][j] = x[(size_t)v * 64 + j];
        ns[slot][j] = nmean[(size_t)v * 64 + j];
    }
    __syncthreads();
    float acc = bj;
    if (valid) {
#pragma unroll
        for (int k = 0; k < 64; ++k) {
            acc += xs[slot][k] * Ws[k * 64 + j];
            acc += ns[slot][k] * Wn[k * 64 + j];
        }
        acc = fmaxf(acc, 0.0f);
        h[(size_t)v * 64 + j] = acc;
        hs[slot][j] = acc;
    }
    __syncthreads();
    if (valid && j < 32) {
        float ga = 0.0f;
#pragma unroll
        for (int k = 0; k < 64; ++k) ga += hs[slot][k] * W2[k * 32 + j];
        g[(size_t)v * 32 + j] = ga;
    }
}

// ---------------- Layer 2: out = h@Ws2 + nmean_g + b2 ----------------
__global__ __launch_bounds__(256)
void sage_layer2(const float* __restrict__ h, const float* __restrict__ nmean_g,
                 const float* __restrict__ Ws2, const float* __restrict__ b2,
                 float* __restrict__ out) {
    __shared__ float Ws[64 * 32];
    __shared__ float hsh[8][64];
    for (int i = threadIdx.x; i < 64 * 32; i += 256) Ws[i] = Ws2[i];
    const int j = threadIdx.x & 31;
    const int slot = threadIdx.x >> 5;
    const float bj = b2[j];
    __syncthreads();

    const int v = blockIdx.x * 8 + slot;
    const bool valid = (v < N_NODES);
    if (valid) {
        hsh[slot][j]      = h[(size_t)v * 64 + j];
        hsh[slot][j + 32] = h[(size_t)v * 64 + j + 32];
    }
    __syncthreads();
    if (valid) {
        float acc = bj + nmean_g[(size_t)v * 32 + j];
#pragma unroll
        for (int k = 0; k < 64; ++k) acc += hsh[slot][k] * Ws[k * 32 + j];
        out[(size_t)v * 32 + j] = acc;
    }
}

extern "C" void kernel_launch(void* const* d_in, const int* in_sizes, int n_in,
                              void* d_out, int out_size, void* d_ws, size_t ws_size,
                              hipStream_t stream) {
    const float* features = (const float*)d_in[0];
    const float* W_self1  = (const float*)d_in[1];
    const float* W_neigh1 = (const float*)d_in[2];
    const float* b1       = (const float*)d_in[3];
    const float* W_self2  = (const float*)d_in[4];
    const float* W_neigh2 = (const float*)d_in[5];
    const float* b2       = (const float*)d_in[6];
    const int*   src      = (const int*)d_in[7];
    const int*   dst      = (const int*)d_in[8];
    float*       out      = (float*)d_out;

    // Workspace layout
    float* agg    = (float*)d_ws;                    // N*64 (reused as 32-wide agg for layer 2)
    float* h      = agg + (size_t)N_NODES * 64;      // N*64
    float* g      = h   + (size_t)N_NODES * 64;      // N*32
    int* counts   = (int*)(g + (size_t)N_NODES * 32);// N
    int* row_ptr  = counts + N_NODES;                // N
    int* cursor   = row_ptr + N_NODES;               // N
    int* csr_src  = cursor + N_NODES;                // E
    int* partials = csr_src + N_EDGES;               // SCAN_BLOCKS (<256)

    // ---- CSR build (by dst) ----
    hipMemsetAsync(counts, 0, N_NODES * sizeof(int), stream);
    hist_kernel<<<(N_EDGES + 255) / 256, 256, 0, stream>>>(dst, counts);
    scan_blocks_kernel<<<SCAN_BLOCKS, 256, 0, stream>>>(counts, partials);
    scan_top_kernel<<<1, 64, 0, stream>>>(partials);
    scan_apply_kernel<<<SCAN_BLOCKS, 256, 0, stream>>>(counts, partials, row_ptr, cursor);
    fill_kernel<<<(N_EDGES + 255) / 256, 256, 0, stream>>>(src, dst, cursor, csr_src);

    // ---- Layer 1 ----
    gather_mean<64><<<(N_NODES + 3) / 4, 256, 0, stream>>>(features, row_ptr, counts, csr_src, agg);
    sage_layer1_fused<<<(N_NODES + 3) / 4, 256, 0, stream>>>(
        features, agg, W_self1, W_neigh1, b1, W_neigh2, h, g);

    // ---- Layer 2 (aggregate pre-transformed g, 32-wide) ----
    gather_mean<32><<<(N_NODES + 7) / 8, 256, 0, stream>>>(g, row_ptr, counts, csr_src, agg);
    sage_layer2<<<(N_NODES + 7) / 8, 256, 0, stream>>>(h, agg, W_self2, b2, out);
}

// Round 3
// 263.331 us; speedup vs baseline: 2.0669x; 1.2098x over previous
//
#include <hip/hip_runtime.h>

#define N_NODES 50000
#define N_EDGES 800000
#define SCAN_BLOCKS 196   // ceil(50000/256)

// ---------------- CSR build ----------------

__global__ __launch_bounds__(256)
void hist_kernel(const int* __restrict__ dst, int* __restrict__ counts) {
    int e = blockIdx.x * blockDim.x + threadIdx.x;
    if (e < N_EDGES) atomicAdd(&counts[dst[e]], 1);
}

__global__ __launch_bounds__(256)
void scan_blocks_kernel(const int* __restrict__ counts, int* __restrict__ partials) {
    __shared__ int buf[256];
    int i = blockIdx.x * 256 + threadIdx.x;
    buf[threadIdx.x] = (i < N_NODES) ? counts[i] : 0;
    __syncthreads();
    for (int off = 128; off > 0; off >>= 1) {
        if (threadIdx.x < off) buf[threadIdx.x] += buf[threadIdx.x + off];
        __syncthreads();
    }
    if (threadIdx.x == 0) partials[blockIdx.x] = buf[0];
}

__global__ void scan_top_kernel(int* __restrict__ partials) {
    if (threadIdx.x == 0 && blockIdx.x == 0) {
        int acc = 0;
        for (int b = 0; b < SCAN_BLOCKS; ++b) {
            int v = partials[b];
            partials[b] = acc;   // exclusive
            acc += v;
        }
    }
}

__global__ __launch_bounds__(256)
void scan_apply_kernel(const int* __restrict__ counts, const int* __restrict__ offsets,
                       int* __restrict__ row_ptr, int* __restrict__ cursor) {
    __shared__ int buf[256];
    int t = threadIdx.x;
    int i = blockIdx.x * 256 + t;
    int v = (i < N_NODES) ? counts[i] : 0;
    buf[t] = v;
    __syncthreads();
    for (int off = 1; off < 256; off <<= 1) {
        int add = (t >= off) ? buf[t - off] : 0;
        __syncthreads();
        buf[t] += add;
        __syncthreads();
    }
    if (i < N_NODES) {
        int rp = offsets[blockIdx.x] + buf[t] - v;   // exclusive scan
        row_ptr[i] = rp;
        cursor[i]  = rp;
    }
}

__global__ __launch_bounds__(256)
void fill_kernel(const int* __restrict__ src, const int* __restrict__ dst,
                 int* __restrict__ cursor, int* __restrict__ csr_src) {
    int e = blockIdx.x * blockDim.x + threadIdx.x;
    if (e < N_EDGES) {
        int d = dst[e];
        int pos = atomicAdd(&cursor[d], 1);
        csr_src[pos] = src[e];
    }
}

// ---------------- Register-tiled fp32 GEMM: C[N,F] = A[N,64] @ [B1|B2] ----------------
// F in {64,128}. Block tile: 64 nodes x F cols. Thread tile: 4 m x (F/16) n,
// n split into HALVES float4 groups at stride 64 to keep LDS reads 2-way max.
template <int F>
__global__ __launch_bounds__(256)
void gemm_cat(const float* __restrict__ A,
              const float* __restrict__ B1,   // [64, F/2]
              const float* __restrict__ B2,   // [64, F/2]
              float* __restrict__ C) {
    constexpr int H = F / 2;
    constexpr int HALVES = F / 64;          // 1 or 2
    __shared__ float As[64][68];            // transposed A tile, padded (4-aligned rows)
    __shared__ float Bs[64][F];

    // stage B (both halves)
    for (int i = threadIdx.x; i < 64 * H; i += 256) {
        int k = i / H, j = i % H;
        Bs[k][j]     = B1[i];
        Bs[k][j + H] = B2[i];
    }
    // stage A transposed: thread reads float4 of a row, scatters to 4 As rows
    const int m0 = blockIdx.x * 64;
    {
        int mloc = threadIdx.x >> 4;          // 0..15
        int k4   = (threadIdx.x & 15) * 4;    // 0..60
#pragma unroll
        for (int it = 0; it < 4; ++it) {
            int m  = mloc + it * 16;
            int gm = m0 + m;
            float4 a = (gm < N_NODES) ? *(const float4*)&A[(size_t)gm * 64 + k4]
                                      : make_float4(0.f, 0.f, 0.f, 0.f);
            As[k4 + 0][m] = a.x; As[k4 + 1][m] = a.y;
            As[k4 + 2][m] = a.z; As[k4 + 3][m] = a.w;
        }
    }
    __syncthreads();

    const int tm  = ((threadIdx.x >> 4) & 3) * 4 + (threadIdx.x >> 6) * 16;  // 0..60
    const int tn4 = (threadIdx.x & 15) * 4;                                   // 0..60

    float acc[4][HALVES][4];
#pragma unroll
    for (int mi = 0; mi < 4; ++mi)
#pragma unroll
        for (int hh = 0; hh < HALVES; ++hh)
#pragma unroll
            for (int ni = 0; ni < 4; ++ni) acc[mi][hh][ni] = 0.f;

#pragma unroll 8
    for (int k = 0; k < 64; ++k) {
        float4 a = *(const float4*)&As[k][tm];
        float4 b[HALVES];
#pragma unroll
        for (int hh = 0; hh < HALVES; ++hh)
            b[hh] = *(const float4*)&Bs[k][tn4 + hh * 64];
        const float am[4] = {a.x, a.y, a.z, a.w};
#pragma unroll
        for (int mi = 0; mi < 4; ++mi) {
#pragma unroll
            for (int hh = 0; hh < HALVES; ++hh) {
                acc[mi][hh][0] += am[mi] * b[hh].x;
                acc[mi][hh][1] += am[mi] * b[hh].y;
                acc[mi][hh][2] += am[mi] * b[hh].z;
                acc[mi][hh][3] += am[mi] * b[hh].w;
            }
        }
    }

#pragma unroll
    for (int mi = 0; mi < 4; ++mi) {
        int gm = m0 + tm + mi;
        if (gm < N_NODES) {
#pragma unroll
            for (int hh = 0; hh < HALVES; ++hh)
                *(float4*)&C[(size_t)gm * F + tn4 + hh * 64] = *(float4*)&acc[mi][hh][0];
        }
    }
}

// ---------------- Gather mean + fused epilogue ----------------
// T: [N, 2F]; self part cols [0,F), neighbor-transformed part cols [F,2F).
// out[v] = act( T[v, :F] + mean_{u in N(v)} T[u, F:] + bias )
// One wave per node. LPR = F/4 lanes per row (float4 each); R = 64/LPR rows in flight.
template <int F, bool RELU>
__global__ __launch_bounds__(256)
void gather_epilogue(const float* __restrict__ T,
                     const int* __restrict__ row_ptr, const int* __restrict__ counts,
                     const int* __restrict__ csr_src, const float* __restrict__ bias,
                     float* __restrict__ out) {
    constexpr int LPR = F / 4;
    constexpr int R   = 64 / LPR;
    int wave = (blockIdx.x * blockDim.x + threadIdx.x) >> 6;   // = node id
    int lane = threadIdx.x & 63;
    int r = lane / LPR;
    int c = lane % LPR;
    int v = wave;
    if (v >= N_NODES) return;
    int start = row_ptr[v];
    int cnt   = counts[v];

    float ax = 0.f, ay = 0.f, az = 0.f, aw = 0.f;
    for (int t = r; t < cnt; t += R) {
        int s = csr_src[start + t];
        float4 p = *(const float4*)&T[(size_t)s * (2 * F) + F + c * 4];
        ax += p.x; ay += p.y; az += p.z; aw += p.w;
    }
#pragma unroll
    for (int off = LPR; off < 64; off <<= 1) {
        ax += __shfl_xor(ax, off);
        ay += __shfl_xor(ay, off);
        az += __shfl_xor(az, off);
        aw += __shfl_xor(aw, off);
    }
    if (r == 0) {
        float inv = 1.0f / (float)max(cnt, 1);
        float4 self = *(const float4*)&T[(size_t)v * (2 * F) + c * 4];
        float4 b4   = *(const float4*)&bias[c * 4];
        float4 o;
        o.x = self.x + ax * inv + b4.x;
        o.y = self.y + ay * inv + b4.y;
        o.z = self.z + az * inv + b4.z;
        o.w = self.w + aw * inv + b4.w;
        if (RELU) {
            o.x = fmaxf(o.x, 0.f); o.y = fmaxf(o.y, 0.f);
            o.z = fmaxf(o.z, 0.f); o.w = fmaxf(o.w, 0.f);
        }
        *(float4*)&out[(size_t)v * F + c * 4] = o;
    }
}

extern "C" void kernel_launch(void* const* d_in, const int* in_sizes, int n_in,
                              void* d_out, int out_size, void* d_ws, size_t ws_size,
                              hipStream_t stream) {
    const float* features = (const float*)d_in[0];
    const float* W_self1  = (const float*)d_in[1];
    const float* W_neigh1 = (const float*)d_in[2];
    const float* b1       = (const float*)d_in[3];
    const float* W_self2  = (const float*)d_in[4];
    const float* W_neigh2 = (const float*)d_in[5];
    const float* b2       = (const float*)d_in[6];
    const int*   src      = (const int*)d_in[7];
    const int*   dst      = (const int*)d_in[8];
    float*       out      = (float*)d_out;

    // Workspace layout:
    //   P : N*128 floats (25.6 MB)  -- layer-1 concat transform; reused as Q (N*64) later
    //   h : N*64  floats (12.8 MB)
    //   ints: counts, row_ptr, cursor (N each), csr_src (E), partials
    float* P = (float*)d_ws;
    float* Q = P;                                   // alias: P dead after gather_h
    float* h = P + (size_t)N_NODES * 128;
    int* counts   = (int*)(h + (size_t)N_NODES * 64);
    int* row_ptr  = counts + N_NODES;
    int* cursor   = row_ptr + N_NODES;
    int* csr_src  = cursor + N_NODES;
    int* partials = csr_src + N_EDGES;

    // ---- CSR build (by dst) ----
    hipMemsetAsync(counts, 0, N_NODES * sizeof(int), stream);
    hist_kernel<<<(N_EDGES + 255) / 256, 256, 0, stream>>>(dst, counts);
    scan_blocks_kernel<<<SCAN_BLOCKS, 256, 0, stream>>>(counts, partials);
    scan_top_kernel<<<1, 64, 0, stream>>>(partials);
    scan_apply_kernel<<<SCAN_BLOCKS, 256, 0, stream>>>(counts, partials, row_ptr, cursor);
    fill_kernel<<<(N_EDGES + 255) / 256, 256, 0, stream>>>(src, dst, cursor, csr_src);

    const int gemm_blocks   = (N_NODES + 63) / 64;   // 782
    const int gather_blocks = (N_NODES + 3) / 4;     // 4 waves/block, 1 node/wave

    // ---- Layer 1: P = x @ [Ws1|Wn1]; h = relu(P_self + mean(P_neigh[src]) + b1) ----
    gemm_cat<128><<<gemm_blocks, 256, 0, stream>>>(features, W_self1, W_neigh1, P);
    gather_epilogue<64, true><<<gather_blocks, 256, 0, stream>>>(
        P, row_ptr, counts, csr_src, b1, h);

    // ---- Layer 2: Q = h @ [Ws2|Wn2]; out = Q_self + mean(Q_neigh[src]) + b2 ----
    gemm_cat<64><<<gemm_blocks, 256, 0, stream>>>(h, W_self2, W_neigh2, Q);
    gather_epilogue<32, false><<<gather_blocks, 256, 0, stream>>>(
        Q, row_ptr, counts, csr_src, b2, out);
}